// Round 11
// baseline (186.288 us; speedup 1.0000x reference)
//
#include <hip/hip_runtime.h>
#include <math.h>

typedef _Float16 half_t;
typedef _Float16 half8 __attribute__((ext_vector_type(8)));
typedef _Float16 half4v __attribute__((ext_vector_type(4)));
typedef float float4v __attribute__((ext_vector_type(4)));
typedef float float16v __attribute__((ext_vector_type(16)));

#define AS1 __attribute__((address_space(1)))
#define AS3 __attribute__((address_space(3)))

#define MFMA16(a, b, c) __builtin_amdgcn_mfma_f32_16x16x32_f16((a), (b), (c), 0, 0, 0)
#define MFMA32(a, b, c) __builtin_amdgcn_mfma_f32_32x32x16_f16((a), (b), (c), 0, 0, 0)

__device__ __forceinline__ void gload16(const half_t* g, half_t* l) {
    __builtin_amdgcn_global_load_lds((const AS1 void*)g, (AS3 void*)l, 16, 0, 0);
}

__device__ __forceinline__ int iclamp(int v, int lo, int hi) {
    return v < lo ? lo : (v > hi ? hi : v);
}

__device__ __forceinline__ half4v shfl32_h4(half4v v) {
    union { half4v h; int i[2]; } u;
    u.h = v;
    u.i[0] = __shfl_xor(u.i[0], 32);
    u.i[1] = __shfl_xor(u.i[1], 32);
    return u.h;
}

// =====================================================================
// cast: fp32 -> fp16 for q, W_in, W_out, rel_pe (padded to 160 rows)
// =====================================================================
__global__ __launch_bounds__(256) void cast_kernel(
    const float* __restrict__ q, const float* __restrict__ w_in,
    const float* __restrict__ w_out, const float* __restrict__ pe,
    half_t* __restrict__ q16, half_t* __restrict__ w16,
    half_t* __restrict__ wo16, half_t* __restrict__ pe16)
{
    const int tid = blockIdx.x * 256 + threadIdx.x;
    const int stride = gridDim.x * 256;
    for (int i = tid; i < 1048576; i += stride) {
        float4 v = ((const float4*)q)[i];
        *(half4v*)(q16 + (size_t)i * 4) =
            (half4v){(half_t)v.x, (half_t)v.y, (half_t)v.z, (half_t)v.w};
    }
    for (int i = tid; i < 786432; i += stride) {
        float4 v = ((const float4*)w_in)[i];
        *(half4v*)(w16 + (size_t)i * 4) =
            (half4v){(half_t)v.x, (half_t)v.y, (half_t)v.z, (half_t)v.w};
    }
    for (int i = tid; i < 262144; i += stride) {
        float4 v = ((const float4*)w_out)[i];
        *(half4v*)(wo16 + (size_t)i * 4) =
            (half4v){(half_t)v.x, (half_t)v.y, (half_t)v.z, (half_t)v.w};
    }
    for (int i = tid; i < 2064; i += stride) {
        float4 v = ((const float4*)pe)[i];
        *(half4v*)(pe16 + (size_t)i * 4) =
            (half4v){(half_t)v.x, (half_t)v.y, (half_t)v.z, (half_t)v.w};
    }
    for (int i = tid; i < 496; i += stride) {   // pad rows 129..159 = 0
        *(half4v*)(pe16 + 8256 + (size_t)i * 4) = (half4v){0, 0, 0, 0};
    }
}

// =====================================================================
// fp16 MFMA NT GEMM, 128x128 tile, BK=64 (was 32: halves barrier count,
// 32 KB LDS still 3+ blocks/CU). 256 thr (4 waves in 2x2).
// 1-D grid, XCD-aware rectangle mapping.
// =====================================================================
__global__ __launch_bounds__(256) void qkv_gemm(
    const half_t* __restrict__ A, const half_t* __restrict__ W,
    const float* __restrict__ bias,
    half_t* __restrict__ qh, half_t* __restrict__ kh, half_t* __restrict__ vt)
{
    __shared__ half_t As[128 * 64];
    __shared__ half_t Bs[128 * 64];
    const int K = 1024;
    const int tid = threadIdx.x, lane = tid & 63, wid = tid >> 6;
    const int wm = wid & 1, wn = wid >> 1;
    const int bid = blockIdx.x;
    const int xcd = bid & 7, idx = bid >> 3;
    const int m0 = (((xcd >> 1) << 3) + (idx & 7)) * 128;
    const int n0 = (((xcd & 1) * 12) + (idx >> 3)) * 128;

    // staging: 1024 16B-slots per matrix (8 slots/row of 64 halves)
    const half_t* gA[4]; const half_t* gB[4];
    half_t* lA[4]; half_t* lB[4];
#pragma unroll
    for (int c = 0; c < 4; ++c) {
        int slot0 = wid * 256 + c * 64;
        int slot = slot0 + lane;
        int row = slot >> 3;
        int ch = (slot & 7) ^ (row & 7);
        gA[c] = A + (size_t)(m0 + row) * K + ch * 8;
        gB[c] = W + (size_t)(n0 + row) * K + ch * 8;
        lA[c] = As + slot0 * 8;
        lB[c] = Bs + slot0 * 8;
    }
    int aOff[4][2], bOff[4][2];
#pragma unroll
    for (int i = 0; i < 4; ++i)
#pragma unroll
        for (int ks = 0; ks < 2; ++ks) {
            int ra = wm * 64 + i * 16 + (lane & 15);
            aOff[i][ks] = ra * 64 + (((ks * 4 + (lane >> 4)) ^ (ra & 7)) * 8);
            int rb = wn * 64 + i * 16 + (lane & 15);
            bOff[i][ks] = rb * 64 + (((ks * 4 + (lane >> 4)) ^ (rb & 7)) * 8);
        }
    float4v acc[4][4];
#pragma unroll
    for (int i = 0; i < 4; ++i)
#pragma unroll
        for (int j = 0; j < 4; ++j) acc[i][j] = (float4v){0.f, 0.f, 0.f, 0.f};

    for (int k0 = 0; k0 < K; k0 += 64) {
        __syncthreads();
#pragma unroll
        for (int c = 0; c < 4; ++c) {
            gload16(gA[c], lA[c]); gload16(gB[c], lB[c]);
            gA[c] += 64; gB[c] += 64;
        }
        __syncthreads();
#pragma unroll
        for (int ks = 0; ks < 2; ++ks) {
            half8 af[4], bf[4];
#pragma unroll
            for (int i = 0; i < 4; ++i) af[i] = *(const half8*)(As + aOff[i][ks]);
#pragma unroll
            for (int j = 0; j < 4; ++j) bf[j] = *(const half8*)(Bs + bOff[j][ks]);
#pragma unroll
            for (int i = 0; i < 4; ++i)
#pragma unroll
                for (int j = 0; j < 4; ++j)
                    acc[i][j] = MFMA16(af[i], bf[j], acc[i][j]);
        }
    }

    const int part = n0 >> 10;
#pragma unroll
    for (int ni = 0; ni < 4; ++ni) {
        const int col = n0 + wn * 64 + ni * 16 + (lane & 15);
        const float bv = bias[col];
        const int hh = (col >> 6) & 15, d = col & 63;
#pragma unroll
        for (int mi = 0; mi < 4; ++mi) {
            const int r0 = m0 + wm * 64 + mi * 16 + ((lane >> 4) << 2);
            const int bb = r0 >> 10, l0 = r0 & 1023;
            if (part == 0) {
#pragma unroll
                for (int r = 0; r < 4; ++r)
                    qh[(((size_t)(bb * 16 + hh) * 1024) + l0 + r) * 64 + d] =
                        (half_t)((acc[mi][ni][r] + bv) * 0.125f);
            } else if (part == 1) {
#pragma unroll
                for (int r = 0; r < 4; ++r)
                    kh[(((size_t)(bb * 16 + hh) * 1024) + l0 + r) * 64 + d] =
                        (half_t)(acc[mi][ni][r] + bv);
            } else {
                half4v pk;
#pragma unroll
                for (int r = 0; r < 4; ++r) pk[r] = (half_t)(acc[mi][ni][r] + bv);
                *(half4v*)(vt + ((size_t)(bb * 16 + hh) * 64 + d) * 1024 + l0) = pk;
            }
        }
    }
}

// =====================================================================
// out GEMM: 128x64 tiles -> 512 blocks (2/CU). (R9 version — banked win.)
// =====================================================================
__global__ __launch_bounds__(256) void out_gemm(
    const half_t* __restrict__ A, const half_t* __restrict__ W,
    const float* __restrict__ bias, float* __restrict__ C)
{
    __shared__ half_t As[128 * 32];
    __shared__ half_t Bs[64 * 32];
    const int K = 1024;
    const int tid = threadIdx.x, lane = tid & 63, wid = tid >> 6;
    const int wm = wid & 1, wn = wid >> 1;
    const int bid = blockIdx.x;
    const int xcd = bid & 7, idx = bid >> 3;
    const int m0 = ((xcd << 2) + (idx >> 4)) * 128;
    const int n0 = (idx & 15) * 64;

    const half_t* gA[2]; const half_t* gB1;
    half_t* lA[2]; half_t* lB1;
    {
        const int base = wid * 128;
#pragma unroll
        for (int c = 0; c < 2; ++c) {
            int slot = base + c * 64 + lane;
            int row = slot >> 2;
            int ch = (slot & 3) ^ ((row >> 1) & 3);
            gA[c] = A + (size_t)(m0 + row) * K + ch * 8;
            lA[c] = As + (base + c * 64) * 8;
        }
        int slotB = wid * 64 + lane;
        int rowB = slotB >> 2;
        int chB = (slotB & 3) ^ ((rowB >> 1) & 3);
        gB1 = W + (size_t)(n0 + rowB) * K + chB * 8;
        lB1 = Bs + (wid * 64) * 8;
    }
    int aOff[4], bOff[2];
#pragma unroll
    for (int i = 0; i < 4; ++i) {
        int ra = wm * 64 + i * 16 + (lane & 15);
        aOff[i] = ra * 32 + (((lane >> 4) ^ ((ra >> 1) & 3)) * 8);
    }
#pragma unroll
    for (int j = 0; j < 2; ++j) {
        int rb = wn * 32 + j * 16 + (lane & 15);
        bOff[j] = rb * 32 + (((lane >> 4) ^ ((rb >> 1) & 3)) * 8);
    }
    float4v acc[4][2];
#pragma unroll
    for (int i = 0; i < 4; ++i)
#pragma unroll
        for (int j = 0; j < 2; ++j) acc[i][j] = (float4v){0.f, 0.f, 0.f, 0.f};

    for (int k0 = 0; k0 < K; k0 += 32) {
        __syncthreads();
        gload16(gA[0], lA[0]); gload16(gA[1], lA[1]);
        gload16(gB1, lB1);
        gA[0] += 32; gA[1] += 32; gB1 += 32;
        __syncthreads();
        half8 af[4], bf[2];
#pragma unroll
        for (int i = 0; i < 4; ++i) af[i] = *(const half8*)(As + aOff[i]);
#pragma unroll
        for (int j = 0; j < 2; ++j) bf[j] = *(const half8*)(Bs + bOff[j]);
#pragma unroll
        for (int i = 0; i < 4; ++i)
#pragma unroll
            for (int j = 0; j < 2; ++j)
                acc[i][j] = MFMA16(af[i], bf[j], acc[i][j]);
    }

#pragma unroll
    for (int ni = 0; ni < 2; ++ni) {
        const int col = n0 + wn * 32 + ni * 16 + (lane & 15);
        const float bv = bias[col];
#pragma unroll
        for (int mi = 0; mi < 4; ++mi) {
            const int r0 = m0 + wm * 64 + mi * 16 + ((lane >> 4) << 2);
#pragma unroll
            for (int r = 0; r < 4; ++r)
                C[(size_t)(r0 + r) * 1024 + col] = acc[mi][ni][r] + bv;
        }
    }
}

// =====================================================================
// MFMA flash attention v5: 32x32x16, 32 q-rows/wave, 128-q blocks,
// dbuf KV (single barrier/iter, R4-proven), and NO P LDS ROUND-TRIP:
// the C^T->B-operand transform is done in-register via shfl_xor(32)
// (thread (ql,hl) holds P kv-quads of parity hl; the missing-parity
// quads live in lane^32 at the same register index — 8 dword shuffles).
// Fixed-max softmax, bias folded into MFMA C-init, skewed bias table.
// Grid 512: 8 q-blocks of one (b,h) share an XCD (K/V L2 locality).
// =====================================================================
__global__ __launch_bounds__(256) void attn_mfma(
    const half_t* __restrict__ qh, const half_t* __restrict__ kh,
    const half_t* __restrict__ vt, const half_t* __restrict__ pe,
    half_t* __restrict__ ao)
{
    __shared__ half_t KV[2 * 8192];        // dbuf [K 64x64 | V^T 64x64] swizzled
    __shared__ half_t R2[4 * 32 * 172];    // per-wave skewed bias, stride 172

    const int tid = threadIdx.x, lane = tid & 63, wid = tid >> 6;
    const int hl = lane >> 5, ql = lane & 31;
    const int bid = blockIdx.x;
    const int xcd = bid & 7, idx = bid >> 3;
    const int bh = xcd + ((idx >> 3) << 3);
    const int q0 = (idx & 7) * 128;
    const int h = bh & 15, b = bh >> 4;
    const int i0w = q0 + wid * 32;
    const size_t hbase = (size_t)(b * 16 + h) * 64 * 1024;
    const half_t* Qg = qh + hbase;
    const half_t* Kg = kh + hbase;
    const half_t* Vg = vt + hbase;

    // Q fragment: element [q=ql][d = cc*16 + hl*8 + j]
    const int qrow = i0w + ql;
    half8 qb[4];
#pragma unroll
    for (int cc = 0; cc < 4; ++cc)
        qb[cc] = *(const half8*)(Qg + (size_t)qrow * 64 + cc * 16 + hl * 8);

    // ---- staging pointers (slots 0..511 K, 512..1023 V^T) ----
    const half_t* gS[4]; int lOff[4]; int ginc[4];
#pragma unroll
    for (int c = 0; c < 4; ++c) {
        const int slot0 = wid * 256 + c * 64;
        const int slot = slot0 + lane;
        if (slot0 < 512) {
            int srow = slot >> 3, sch = (slot & 7) ^ (srow & 7);
            gS[c] = Kg + srow * 64 + sch * 8;
            ginc[c] = 64 * 64;
            lOff[c] = slot0 * 8;
        } else {
            int s2 = slot - 512;
            int srow = s2 >> 3, sch = (s2 & 7) ^ (srow & 7);
            gS[c] = Vg + srow * 1024 + sch * 8;
            ginc[c] = 64;
            lOff[c] = 4096 + (slot0 - 512) * 8;
        }
    }
    // issue tile 0 into buf 0 (in flight during R2 build)
#pragma unroll
    for (int c = 0; c < 4; ++c) { gload16(gS[c], KV + lOff[c]); gS[c] += ginc[c]; }

    // ---- build skewed bias table (wave-private): entry[il][ts] ----
    half_t* r2w = R2 + wid * (32 * 172);
#pragma unroll
    for (int j2 = 0; j2 < 5; ++j2) {
        float16v c;
#pragma unroll
        for (int r = 0; r < 16; ++r) c[r] = 0.f;
#pragma unroll
        for (int cc = 0; cc < 4; ++cc) {
            half8 pb = *(const half8*)(pe + (size_t)(j2 * 32 + ql) * 64 + cc * 16 + hl * 8);
            c = MFMA32(qb[cc], pb, c);
        }
        const int col = j2 * 32 + ql;
        if (col < 129) {
#pragma unroll
            for (int reg = 0; reg < 16; ++reg) {
                const int il = (reg & 3) + 8 * (reg >> 2) + 4 * hl;
                const half_t hv = (half_t)(c[reg] - 2.0f);
                if (col == 0) {
                    for (int ts = 0; ts <= il + 4; ++ts) r2w[il * 172 + ts] = hv;
                } else if (col == 128) {
                    for (int ts = il + 132; ts <= il + 139; ++ts) r2w[il * 172 + ts] = hv;
                } else {
                    r2w[il * 172 + col + 4 + il] = hv;
                }
            }
        }
    }

    // ---- frag LDS offsets (within one KV buffer) ----
    int kOff[2][4], vOff[2][4];
#pragma unroll
    for (int t2 = 0; t2 < 2; ++t2)
#pragma unroll
        for (int cc = 0; cc < 4; ++cc) {
            int row = t2 * 32 + ql;
            int ch = (cc * 2 + hl) ^ (row & 7);
            kOff[t2][cc] = row * 64 + ch * 8;
            vOff[t2][cc] = 4096 + row * 64 + ch * 8;
        }

    const int hiC = 128 + ((ql + 3) & ~3);   // per-thread bias clamp (mult of 4)
    const half_t* r2row = r2w + ql * 172;

    float l_r = 0.f;
    float16v oacc[2];
#pragma unroll
    for (int dt = 0; dt < 2; ++dt)
#pragma unroll
        for (int r = 0; r < 16; ++r) oacc[dt][r] = 0.f;

    for (int kt = 0; kt < 16; ++kt) {
        __syncthreads();                   // buf[kt&1] published (vmcnt drain)
        const int cur = (kt & 1) * 8192;
        if (kt < 15) {
            const int nxt = ((kt + 1) & 1) * 8192;
#pragma unroll
            for (int c = 0; c < 4; ++c) { gload16(gS[c], KV + nxt + lOff[c]); gS[c] += ginc[c]; }
        }

        // S^T per 32-kv half-tile; P kept in registers (C^T layout)
        half4v P4[2][4];
#pragma unroll
        for (int t2 = 0; t2 < 2; ++t2) {
            float16v s;
#pragma unroll
            for (int g = 0; g < 4; ++g) {
                int traw = kt * 64 + t2 * 32 + 8 * g + 4 * hl + 64 - i0w;
                int tsb = iclamp(traw, -4, hiC) + 4;
                half4v bh4 = *(const half4v*)(r2row + tsb);
#pragma unroll
                for (int r = 0; r < 4; ++r) s[4 * g + r] = (float)bh4[r];
            }
#pragma unroll
            for (int cc = 0; cc < 4; ++cc) {
                half8 kf = *(const half8*)(KV + cur + kOff[t2][cc]);
                s = MFMA32(kf, qb[cc], s);
            }
#pragma unroll
            for (int g = 0; g < 4; ++g) {
#pragma unroll
                for (int r = 0; r < 4; ++r) {
                    float p = __expf(s[4 * g + r]);
                    l_r += p;
                    P4[t2][g][r] = (half_t)p;
                }
            }
        }

        // in-register C^T -> B transform: quads of the other parity come
        // from lane^32 (same register index); hl selects which reg to send
        half4v rcv[2][2];
#pragma unroll
        for (int t = 0; t < 2; ++t)
#pragma unroll
            for (int k = 0; k < 2; ++k) {
                half4v send = hl ? P4[t][2 * k] : P4[t][2 * k + 1];
                rcv[t][k] = shfl32_h4(send);
            }
        half8 pf[4];
#pragma unroll
        for (int cc = 0; cc < 4; ++cc) {
            const int t = cc >> 1, k = cc & 1;
            half4v lo = hl ? rcv[t][k] : P4[t][2 * k];
            half4v hi = hl ? P4[t][2 * k + 1] : rcv[t][k];
#pragma unroll
            for (int r = 0; r < 4; ++r) { pf[cc][r] = lo[r]; pf[cc][4 + r] = hi[r]; }
        }

        // O^T += V^T · P^T
#pragma unroll
        for (int dt = 0; dt < 2; ++dt)
#pragma unroll
            for (int cc = 0; cc < 4; ++cc) {
                half8 vf = *(const half8*)(KV + cur + vOff[dt][cc]);
                oacc[dt] = MFMA32(vf, pf[cc], oacc[dt]);
            }
    }

    // l: pair lanes (lane, lane^32) share the q column
    l_r += __shfl_xor(l_r, 32);
    const float inv = 1.0f / l_r;

    half_t* aorow = ao + ((size_t)(b * 1024 + i0w + ql)) * 1024 + h * 64;
#pragma unroll
    for (int dt = 0; dt < 2; ++dt)
#pragma unroll
        for (int g = 0; g < 4; ++g) {
            const int d0 = dt * 32 + 8 * g + 4 * hl;
            half4v oh;
#pragma unroll
            for (int r = 0; r < 4; ++r) oh[r] = (half_t)(oacc[dt][4 * g + r] * inv);
            *(half4v*)(aorow + d0) = oh;
        }
}

extern "C" void kernel_launch(void* const* d_in, const int* in_sizes, int n_in,
                              void* d_out, int out_size, void* d_ws, size_t ws_size,
                              hipStream_t stream) {
    const float* q     = (const float*)d_in[0];
    const float* w_in  = (const float*)d_in[1];
    const float* b_in  = (const float*)d_in[2];
    const float* w_out = (const float*)d_in[3];
    const float* b_out = (const float*)d_in[4];
    const float* pe    = (const float*)d_in[5];
    float* out = (float*)d_out;

    half_t* ws = (half_t*)d_ws;
    half_t* q16   = ws;
    half_t* w16   = q16 + 4194304;
    half_t* wo16  = w16 + 3145728;
    half_t* pe16  = wo16 + 1048576;      // 160x64 padded
    half_t* qh16  = pe16 + 10240;
    half_t* kh16  = qh16 + 4194304;
    half_t* vt16  = kh16 + 4194304;
    half_t* ao16  = vt16 + 4194304;

    cast_kernel<<<2048, 256, 0, stream>>>(q, w_in, w_out, pe, q16, w16, wo16, pe16);
    qkv_gemm<<<768, 256, 0, stream>>>(q16, w16, b_in, qh16, kh16, vt16);
    attn_mfma<<<512, 256, 0, stream>>>(qh16, kh16, vt16, pe16, ao16);
    out_gemm<<<512, 256, 0, stream>>>(ao16, wo16, b_out, out);
}